// Round 1
// baseline (814.077 us; speedup 1.0000x reference)
//
#include <hip/hip_runtime.h>
#include <hip/hip_bf16.h>

#define B_  16
#define T_  354
#define N_  64
#define H_  128
#define NS_ 32
#define BN_ (B_*N_)          // 1024 sequences
#define M_  (T_*BN_)         // 362496 positions (q = t*BN + bn)

static __device__ __forceinline__ unsigned short f32_to_bf16(float f) {
    unsigned int u = __float_as_uint(f);
    unsigned int r = 0x7FFFu + ((u >> 16) & 1u);   // RNE
    return (unsigned short)((u + r) >> 16);
}
static __device__ __forceinline__ float bf16_hi(unsigned int packed) {
    return __uint_as_float(packed & 0xFFFF0000u);
}
static __device__ __forceinline__ float bf16_lo(unsigned int packed) {
    return __uint_as_float(packed << 16);
}

// ---------------------------------------------------------------------------
// K0: discretize S4D params.  w = exp(dt*A),  Cd = C*(exp(dt*A)-1)/A
// ---------------------------------------------------------------------------
__global__ void k_params(const float* __restrict__ log_dt,
                         const float* __restrict__ A_re, const float* __restrict__ A_im,
                         const float* __restrict__ C_re, const float* __restrict__ C_im,
                         float* __restrict__ wre, float* __restrict__ wim,
                         float* __restrict__ cre, float* __restrict__ cim) {
    int i = blockIdx.x * blockDim.x + threadIdx.x;
    if (i >= H_ * NS_) return;
    int h = i / NS_;
    float dt  = expf(log_dt[h]);
    float are = A_re[i], aim = A_im[i];
    float dre = are * dt, dim = aim * dt;
    float er  = expf(dre);
    float e_re = er * cosf(dim);
    float e_im = er * sinf(dim);
    // (e-1)/A  = (e-1)*conj(A)/|A|^2
    float m_re = e_re - 1.0f, m_im = e_im;
    float inv  = 1.0f / (are * are + aim * aim);
    float q_re = (m_re * are + m_im * aim) * inv;
    float q_im = (m_im * are - m_re * aim) * inv;
    float c_r = C_re[i], c_i = C_im[i];
    wre[i] = e_re;  wim[i] = e_im;
    cre[i] = c_r * q_re - c_i * q_im;
    cim[i] = c_r * q_im + c_i * q_re;
}

// ---------------------------------------------------------------------------
// K1: SSM recurrence + D-skip + gelu(tanh), one thread per (h, bn).
// All 32 complex states in registers; w/Cd are block-uniform (h = blockIdx.x).
// Writes y as bf16 in layout Y[h][q], q = t*BN + bn (coalesced per t).
// ---------------------------------------------------------------------------
__global__ __launch_bounds__(256, 2) void k_ssm(
        const float* __restrict__ x, const float* __restrict__ W_in,
        const float* __restrict__ b_in, const float* __restrict__ D,
        const float* __restrict__ wre_g, const float* __restrict__ wim_g,
        const float* __restrict__ cre_g, const float* __restrict__ cim_g,
        unsigned short* __restrict__ Y) {
    const int h   = blockIdx.x;
    const int tid = threadIdx.x;
    const int bn  = blockIdx.y * 256 + tid;
    const int b   = bn >> 6, n = bn & 63;

    const float win = W_in[h], bin = b_in[h], dh = D[h];

    float wre[NS_], wim[NS_], cre[NS_], cim[NS_];
#pragma unroll
    for (int m = 0; m < NS_; m++) {
        wre[m] = wre_g[h * NS_ + m];
        wim[m] = wim_g[h * NS_ + m];
        cre[m] = cre_g[h * NS_ + m];
        cim[m] = cim_g[h * NS_ + m];
    }
    float sre[NS_], sim[NS_];
#pragma unroll
    for (int m = 0; m < NS_; m++) { sre[m] = 0.0f; sim[m] = 0.0f; }

    const float* xp = x + b * (T_ * N_) + n;
    unsigned short* yp = Y + (size_t)h * M_ + bn;

    for (int t = 0; t < T_; t++) {
        float u = fmaf(xp[t * N_], win, bin);
        float acc0 = 0.0f, acc1 = 0.0f;
#pragma unroll
        for (int m = 0; m < NS_; m++) {
            float nim = fmaf(wim[m], sre[m], wre[m] * sim[m]);   // uses old sre/sim
            float nre = fmaf(wre[m], sre[m], u);
            nre = fmaf(-wim[m], sim[m], nre);
            sre[m] = nre; sim[m] = nim;
            if (m & 1) { acc1 = fmaf(cre[m], nre, acc1); acc1 = fmaf(-cim[m], nim, acc1); }
            else       { acc0 = fmaf(cre[m], nre, acc0); acc0 = fmaf(-cim[m], nim, acc0); }
        }
        float v = fmaf(2.0f, acc0 + acc1, dh * u);
        // gelu, tanh approximation (JAX default)
        float a  = 0.7978845608028654f * fmaf(0.044715f, v * v * v, v);
        float e  = __expf(2.0f * a);
        float th = 1.0f - 2.0f / (e + 1.0f);
        float g  = 0.5f * v * (1.0f + th);
        yp[t * BN_] = f32_to_bf16(g);
    }
}

// ---------------------------------------------------------------------------
// K2: position-wise  g = W_out·y + b_out, GLU, sum over t  -> node_sum[bn][jh]
// Tile: 128 bn  x 32 jh (so W rows jh and jh+128 both staged), t-chunk of 23.
// fp32 VALU GEMM; y staged in LDS as bf16.
// ---------------------------------------------------------------------------
__global__ __launch_bounds__(256) void k_glu(
        const unsigned short* __restrict__ Y,
        const float* __restrict__ W_out, const float* __restrict__ b_out,
        float* __restrict__ node_sum) {
    __shared__ float W1[H_ * 32];              // [k][j]  fp32, 16 KB
    __shared__ float W2[H_ * 32];              // [k][j]  fp32, 16 KB
    __shared__ unsigned short Yt[H_ * H_];     // [k][bn_local] bf16, 32 KB

    const int tid = threadIdx.x;
    const int BN0 = blockIdx.x * 128;
    const int J0  = blockIdx.y * 32;
    const int t0  = blockIdx.z * 23;

    // stage W_out tiles (transpose to [k][j]); coalesced global reads
    for (int i = tid; i < H_ * 32; i += 256) {
        int j = i >> 7, k = i & 127;
        W1[k * 32 + j] = W_out[(J0 + j) * H_ + k];
        W2[k * 32 + j] = W_out[(128 + J0 + j) * H_ + k];
    }

    const int bn_grp = tid & 31;   // *4 -> bn_local
    const int jh_grp = tid >> 5;   // *4 -> jh offset in tile

    float bo1[4], bo2[4];
#pragma unroll
    for (int ji = 0; ji < 4; ji++) {
        bo1[ji] = b_out[J0 + jh_grp * 4 + ji];
        bo2[ji] = b_out[128 + J0 + jh_grp * 4 + ji];
    }

    float zacc[4][4];
#pragma unroll
    for (int bi = 0; bi < 4; bi++)
#pragma unroll
        for (int ji = 0; ji < 4; ji++) zacc[bi][ji] = 0.0f;

    for (int tt = 0; tt < 23; tt++) {
        int t = t0 + tt;
        if (t >= T_) break;                    // block-uniform
        __syncthreads();                       // Yt reuse guard (+W ready, iter 0)
        // stage y[:, t, bn-tile]: 128 rows x 128 bf16, 8B per thread-iter
        for (int c = tid; c < (H_ * H_) / 4; c += 256) {
            int hh = c >> 5, i4 = (c & 31) * 4;
            uint2 v = *(const uint2*)(Y + (size_t)hh * M_ + t * BN_ + BN0 + i4);
            *(uint2*)&Yt[hh * 128 + i4] = v;
        }
        __syncthreads();

        float g1[4][4], g2[4][4];
#pragma unroll
        for (int bi = 0; bi < 4; bi++)
#pragma unroll
            for (int ji = 0; ji < 4; ji++) { g1[bi][ji] = 0.0f; g2[bi][ji] = 0.0f; }

#pragma unroll 4
        for (int k = 0; k < H_; k++) {
            uint2 yv = *(const uint2*)&Yt[k * 128 + bn_grp * 4];
            float y4[4];
            y4[0] = bf16_lo(yv.x); y4[1] = bf16_hi(yv.x);
            y4[2] = bf16_lo(yv.y); y4[3] = bf16_hi(yv.y);
            float4 w1v = *(const float4*)&W1[k * 32 + jh_grp * 4];
            float4 w2v = *(const float4*)&W2[k * 32 + jh_grp * 4];
            const float w1a[4] = {w1v.x, w1v.y, w1v.z, w1v.w};
            const float w2a[4] = {w2v.x, w2v.y, w2v.z, w2v.w};
#pragma unroll
            for (int bi = 0; bi < 4; bi++)
#pragma unroll
                for (int ji = 0; ji < 4; ji++) {
                    g1[bi][ji] = fmaf(y4[bi], w1a[ji], g1[bi][ji]);
                    g2[bi][ji] = fmaf(y4[bi], w2a[ji], g2[bi][ji]);
                }
        }
        // GLU + pool over t
#pragma unroll
        for (int bi = 0; bi < 4; bi++)
#pragma unroll
            for (int ji = 0; ji < 4; ji++) {
                float a  = g1[bi][ji] + bo1[ji];
                float bb = g2[bi][ji] + bo2[ji];
                float sg = 1.0f / (1.0f + __expf(-bb));
                zacc[bi][ji] += a * sg;
            }
    }

#pragma unroll
    for (int bi = 0; bi < 4; bi++)
#pragma unroll
        for (int ji = 0; ji < 4; ji++) {
            int bn = BN0 + bn_grp * 4 + bi;
            int jh = J0 + jh_grp * 4 + ji;
            atomicAdd(&node_sum[bn * H_ + jh], zacc[bi][ji]);
        }
}

// ---------------------------------------------------------------------------
// K3: logits[b] = (1/(T*N)) * sum_{n,h} node_sum[b*64+n][h] * W_cls[h] + b_cls
// ---------------------------------------------------------------------------
__global__ void k_cls(const float* __restrict__ node_sum,
                      const float* __restrict__ W_cls, const float* __restrict__ b_cls,
                      float* __restrict__ out) {
    const int b = blockIdx.x, tid = threadIdx.x;
    float s = 0.0f;
    for (int i = tid; i < N_ * H_; i += 256)
        s += node_sum[b * (N_ * H_) + i] * W_cls[i & (H_ - 1)];
    __shared__ float red[256];
    red[tid] = s;
    __syncthreads();
    for (int off = 128; off > 0; off >>= 1) {
        if (tid < off) red[tid] += red[tid + off];
        __syncthreads();
    }
    if (tid == 0) out[b] = red[0] * (1.0f / (354.0f * 64.0f)) + b_cls[0];
}

// ---------------------------------------------------------------------------
extern "C" void kernel_launch(void* const* d_in, const int* in_sizes, int n_in,
                              void* d_out, int out_size, void* d_ws, size_t ws_size,
                              hipStream_t stream) {
    const float* x      = (const float*)d_in[0];
    const float* W_in   = (const float*)d_in[1];
    const float* b_in   = (const float*)d_in[2];
    const float* log_dt = (const float*)d_in[3];
    const float* A_re   = (const float*)d_in[4];
    const float* A_im   = (const float*)d_in[5];
    const float* C_re   = (const float*)d_in[6];
    const float* C_im   = (const float*)d_in[7];
    const float* D      = (const float*)d_in[8];
    const float* W_out  = (const float*)d_in[9];
    const float* b_out  = (const float*)d_in[10];
    const float* W_cls  = (const float*)d_in[11];
    const float* b_cls  = (const float*)d_in[12];

    float* ws  = (float*)d_ws;
    float* wre = ws;                    // 4096
    float* wim = ws + 4096;             // 4096
    float* cre = ws + 8192;             // 4096
    float* cim = ws + 12288;            // 4096
    float* node_sum = ws + 16384;       // 1024*128 = 131072
    unsigned short* Y = (unsigned short*)(ws + 16384 + 131072);  // 128*362496 bf16 ~ 93 MB

    hipMemsetAsync(node_sum, 0, (size_t)BN_ * H_ * sizeof(float), stream);
    k_params<<<dim3((H_ * NS_ + 255) / 256), dim3(256), 0, stream>>>(
        log_dt, A_re, A_im, C_re, C_im, wre, wim, cre, cim);
    k_ssm<<<dim3(H_, BN_ / 256), dim3(256), 0, stream>>>(
        x, W_in, b_in, D, wre, wim, cre, cim, Y);
    k_glu<<<dim3(BN_ / 128, 4, 16), dim3(256), 0, stream>>>(Y, W_out, b_out, node_sum);
    k_cls<<<dim3(B_), dim3(256), 0, stream>>>(node_sum, W_cls, b_cls, (float*)d_out);
}

// Round 2
// 373.423 us; speedup vs baseline: 2.1800x; 2.1800x over previous
//
#include <hip/hip_runtime.h>
#include <hip/hip_bf16.h>

// R2: k_glu fp32-VALU GEMM (441us, MfmaUtil=0) -> bf16 MFMA with reg-resident
// W-fragments + global-streamed Y-fragments. Y layout changed to [q][h] so
// a-frag loads coalesce; k_ssm restructured to (128h x 2bn) blocks to write it.

#define B_  16
#define T_  354
#define N_  64
#define H_  128
#define NS_ 32
#define BN_ (B_*N_)          // 1024 sequences
#define M_  (T_*BN_)         // 362496 positions (q = t*BN + bn)
#define TC_ 23               // t-chunk per k_glu block (16 chunks cover 354)

typedef __attribute__((ext_vector_type(8))) short bf16x8;
typedef __attribute__((ext_vector_type(4))) float f32x4;

static __device__ __forceinline__ unsigned short f32_to_bf16(float f) {
    unsigned int u = __float_as_uint(f);
    unsigned int r = 0x7FFFu + ((u >> 16) & 1u);   // RNE
    return (unsigned short)((u + r) >> 16);
}

// ---------------------------------------------------------------------------
// K0: discretize S4D params.  w = exp(dt*A),  Cd = C*(exp(dt*A)-1)/A
// ---------------------------------------------------------------------------
__global__ void k_params(const float* __restrict__ log_dt,
                         const float* __restrict__ A_re, const float* __restrict__ A_im,
                         const float* __restrict__ C_re, const float* __restrict__ C_im,
                         float* __restrict__ wre, float* __restrict__ wim,
                         float* __restrict__ cre, float* __restrict__ cim) {
    int i = blockIdx.x * blockDim.x + threadIdx.x;
    if (i >= H_ * NS_) return;
    int h = i / NS_;
    float dt  = expf(log_dt[h]);
    float are = A_re[i], aim = A_im[i];
    float dre = are * dt, dim = aim * dt;
    float er  = expf(dre);
    float e_re = er * cosf(dim);
    float e_im = er * sinf(dim);
    float m_re = e_re - 1.0f, m_im = e_im;
    float inv  = 1.0f / (are * are + aim * aim);
    float q_re = (m_re * are + m_im * aim) * inv;
    float q_im = (m_im * are - m_re * aim) * inv;
    float c_r = C_re[i], c_i = C_im[i];
    wre[i] = e_re;  wim[i] = e_im;
    cre[i] = c_r * q_re - c_i * q_im;
    cim[i] = c_r * q_im + c_i * q_re;
}

// ---------------------------------------------------------------------------
// K0b: W_out f32 -> bf16 (layout unchanged [j][k], j<256, k<128)
// ---------------------------------------------------------------------------
__global__ void k_wprep(const float* __restrict__ W_out, unsigned short* __restrict__ Wbf) {
    int i = blockIdx.x * blockDim.x + threadIdx.x;
    if (i < 2 * H_ * H_) Wbf[i] = f32_to_bf16(W_out[i]);
}

// ---------------------------------------------------------------------------
// K1: SSM recurrence + D-skip + gelu(tanh).
// Block = 256 threads = 128 h x 2 bn  (h = tid&127, bnl = tid>>7).
// x series for the block's 2 sequences preloaded to LDS (2.8 KB).
// Writes y bf16 in layout Y[q][h], q = t*BN+bn  (h contiguous -> MFMA A-frags).
// ---------------------------------------------------------------------------
__global__ __launch_bounds__(256, 2) void k_ssm(
        const float* __restrict__ x, const float* __restrict__ W_in,
        const float* __restrict__ b_in, const float* __restrict__ D,
        const float* __restrict__ wre_g, const float* __restrict__ wim_g,
        const float* __restrict__ cre_g, const float* __restrict__ cim_g,
        unsigned short* __restrict__ Y) {
    const int tid = threadIdx.x;
    const int h   = tid & 127;
    const int bnl = tid >> 7;
    const int bn0 = blockIdx.x * 2;

    __shared__ float sx[2][T_];
    for (int c = tid; c < 2 * T_; c += 256) {
        int s  = (c >= T_) ? 1 : 0;
        int t  = c - s * T_;
        int bn = bn0 + s;
        sx[s][t] = x[(bn >> 6) * (T_ * N_) + t * N_ + (bn & 63)];
    }

    const float win = W_in[h], bin = b_in[h], dh = D[h];

    float wre[NS_], wim[NS_], cre[NS_], cim[NS_];
#pragma unroll
    for (int m = 0; m < NS_; m++) {
        wre[m] = wre_g[h * NS_ + m];
        wim[m] = wim_g[h * NS_ + m];
        cre[m] = cre_g[h * NS_ + m];
        cim[m] = cim_g[h * NS_ + m];
    }
    float sre[NS_], sim[NS_];
#pragma unroll
    for (int m = 0; m < NS_; m++) { sre[m] = 0.0f; sim[m] = 0.0f; }

    __syncthreads();

    unsigned short* yp = Y + (size_t)(bn0 + bnl) * H_ + h;

    for (int t = 0; t < T_; t++) {
        float u = fmaf(sx[bnl][t], win, bin);
        float acc0 = 0.0f, acc1 = 0.0f;
#pragma unroll
        for (int m = 0; m < NS_; m++) {
            float nim = fmaf(wim[m], sre[m], wre[m] * sim[m]);
            float nre = fmaf(wre[m], sre[m], u);
            nre = fmaf(-wim[m], sim[m], nre);
            sre[m] = nre; sim[m] = nim;
            if (m & 1) { acc1 = fmaf(cre[m], nre, acc1); acc1 = fmaf(-cim[m], nim, acc1); }
            else       { acc0 = fmaf(cre[m], nre, acc0); acc0 = fmaf(-cim[m], nim, acc0); }
        }
        float v = fmaf(2.0f, acc0 + acc1, dh * u);
        // gelu, tanh approximation (JAX default)
        float a  = 0.7978845608028654f * fmaf(0.044715f, v * v * v, v);
        float e  = __expf(2.0f * a);
        float th = 1.0f - 2.0f / (e + 1.0f);
        float g  = 0.5f * v * (1.0f + th);
        yp[(size_t)t * (BN_ * H_)] = f32_to_bf16(g);
    }
}

// ---------------------------------------------------------------------------
// K2: MFMA GEMM  g = W_out·y  (+bias), GLU, pool over t -> node_sum[bn][j].
// D[m=bn][n=j], mfma_f32_16x16x32_bf16.
// Block = 4 waves; wave w owns j in [32w,32w+32) (g1) and +128 (g2):
//   b-frags (W) held in registers across the whole t-loop (64 VGPRs),
//   a-frags (Y) streamed from global (no LDS in the t-loop).
// Block tile: 32 bn x 256 j x TC_ timesteps.
// ---------------------------------------------------------------------------
__global__ __launch_bounds__(256, 2) void k_glu(
        const unsigned short* __restrict__ Ybf,
        const unsigned short* __restrict__ Wbf,
        const float* __restrict__ b_out,
        float* __restrict__ node_sum) {
    __shared__ unsigned short W_lds[128 * 136];   // 34 KB, +8 pad breaks conflicts

    const int tid  = threadIdx.x;
    const int w    = tid >> 6;
    const int lane = tid & 63;
    const int quad = lane >> 4;
    const int l16  = lane & 15;
    const int bn0  = blockIdx.x * 32;
    const int t0   = blockIdx.y * TC_;

    bf16x8 bfrag[4][4];   // [nt][kstep]; nt 0,1 = g1 rows, nt 2,3 = g2 rows

    // stage W in two 128-row phases so LDS stays at 34 KB
    for (int p = 0; p < 2; p++) {
        __syncthreads();
#pragma unroll
        for (int it = 0; it < 16; it++) {
            int c  = it * 256 + tid;
            int r  = c >> 5;
            int k4 = (c & 31) * 4;
            uint2 v = *(const uint2*)(Wbf + (size_t)(p * 128 + r) * 128 + k4);
            *(uint2*)&W_lds[r * 136 + k4] = v;
        }
        __syncthreads();
#pragma unroll
        for (int nt = 0; nt < 2; nt++) {
            int r = 32 * w + 16 * nt + l16;
#pragma unroll
            for (int ks = 0; ks < 4; ks++)
                bfrag[p * 2 + nt][ks] = *(const bf16x8*)&W_lds[r * 136 + ks * 32 + quad * 8];
        }
    }

    float bo1[2], bo2[2];
#pragma unroll
    for (int p = 0; p < 2; p++) {
        bo1[p] = b_out[32 * w + 16 * p + l16];
        bo2[p] = b_out[128 + 32 * w + 16 * p + l16];
    }

    f32x4 zacc[2][2];
#pragma unroll
    for (int mt = 0; mt < 2; mt++)
#pragma unroll
        for (int p = 0; p < 2; p++) zacc[mt][p] = (f32x4){0.f, 0.f, 0.f, 0.f};

    for (int tt = 0; tt < TC_; tt++) {
        int t = t0 + tt;
        if (t >= T_) break;                       // block-uniform
        const unsigned short* yrow = Ybf + (size_t)(t * BN_ + bn0) * H_;

        bf16x8 afrag[2][4];                       // [mt][kstep]
#pragma unroll
        for (int mt = 0; mt < 2; mt++)
#pragma unroll
            for (int ks = 0; ks < 4; ks++)
                afrag[mt][ks] = *(const bf16x8*)(yrow + (size_t)(16 * mt + l16) * H_
                                                 + ks * 32 + quad * 8);

        f32x4 acc[2][4];
#pragma unroll
        for (int mt = 0; mt < 2; mt++)
#pragma unroll
            for (int nt = 0; nt < 4; nt++) acc[mt][nt] = (f32x4){0.f, 0.f, 0.f, 0.f};

#pragma unroll
        for (int ks = 0; ks < 4; ks++)
#pragma unroll
            for (int nt = 0; nt < 4; nt++)
#pragma unroll
                for (int mt = 0; mt < 2; mt++)
                    acc[mt][nt] = __builtin_amdgcn_mfma_f32_16x16x32_bf16(
                        afrag[mt][ks], bfrag[nt][ks], acc[mt][nt], 0, 0, 0);

        // GLU + pool over t (in registers)
#pragma unroll
        for (int mt = 0; mt < 2; mt++)
#pragma unroll
            for (int p = 0; p < 2; p++)
#pragma unroll
                for (int r = 0; r < 4; r++) {
                    float a  = acc[mt][p][r] + bo1[p];
                    float bs = acc[mt][p + 2][r] + bo2[p];
                    float sg = 1.0f / (1.0f + __expf(-bs));
                    zacc[mt][p][r] += a * sg;
                }
    }

#pragma unroll
    for (int mt = 0; mt < 2; mt++)
#pragma unroll
        for (int p = 0; p < 2; p++)
#pragma unroll
            for (int r = 0; r < 4; r++) {
                int bn = bn0 + 16 * mt + quad * 4 + r;
                int j  = 32 * w + 16 * p + l16;
                atomicAdd(&node_sum[bn * H_ + j], zacc[mt][p][r]);
            }
}

// ---------------------------------------------------------------------------
// K3: logits[b] = (1/(T*N)) * sum_{n,h} node_sum[b*64+n][h] * W_cls[h] + b_cls
// ---------------------------------------------------------------------------
__global__ void k_cls(const float* __restrict__ node_sum,
                      const float* __restrict__ W_cls, const float* __restrict__ b_cls,
                      float* __restrict__ out) {
    const int b = blockIdx.x, tid = threadIdx.x;
    float s = 0.0f;
    for (int i = tid; i < N_ * H_; i += 256)
        s += node_sum[b * (N_ * H_) + i] * W_cls[i & (H_ - 1)];
    __shared__ float red[256];
    red[tid] = s;
    __syncthreads();
    for (int off = 128; off > 0; off >>= 1) {
        if (tid < off) red[tid] += red[tid + off];
        __syncthreads();
    }
    if (tid == 0) out[b] = red[0] * (1.0f / (354.0f * 64.0f)) + b_cls[0];
}

// ---------------------------------------------------------------------------
extern "C" void kernel_launch(void* const* d_in, const int* in_sizes, int n_in,
                              void* d_out, int out_size, void* d_ws, size_t ws_size,
                              hipStream_t stream) {
    const float* x      = (const float*)d_in[0];
    const float* W_in   = (const float*)d_in[1];
    const float* b_in   = (const float*)d_in[2];
    const float* log_dt = (const float*)d_in[3];
    const float* A_re   = (const float*)d_in[4];
    const float* A_im   = (const float*)d_in[5];
    const float* C_re   = (const float*)d_in[6];
    const float* C_im   = (const float*)d_in[7];
    const float* D      = (const float*)d_in[8];
    const float* W_out  = (const float*)d_in[9];
    const float* b_out  = (const float*)d_in[10];
    const float* W_cls  = (const float*)d_in[11];
    const float* b_cls  = (const float*)d_in[12];

    float* ws  = (float*)d_ws;
    float* wre = ws;                               // 4096
    float* wim = ws + 4096;
    float* cre = ws + 8192;
    float* cim = ws + 12288;
    float* node_sum = ws + 16384;                  // 1024*128 f32
    unsigned short* Wbf = (unsigned short*)(ws + 16384 + 131072);   // 32768 bf16
    unsigned short* Y   = (unsigned short*)(ws + 16384 + 131072 + 16384);  // ~93 MB

    hipMemsetAsync(node_sum, 0, (size_t)BN_ * H_ * sizeof(float), stream);
    k_params<<<dim3((H_ * NS_ + 255) / 256), dim3(256), 0, stream>>>(
        log_dt, A_re, A_im, C_re, C_im, wre, wim, cre, cim);
    k_wprep<<<dim3(2 * H_ * H_ / 256), dim3(256), 0, stream>>>(W_out, Wbf);
    k_ssm<<<dim3(BN_ / 2), dim3(256), 0, stream>>>(
        x, W_in, b_in, D, wre, wim, cre, cim, Y);
    k_glu<<<dim3(BN_ / 32, (T_ + TC_ - 1) / TC_), dim3(256), 0, stream>>>(
        Y, Wbf, b_out, node_sum);
    k_cls<<<dim3(B_), dim3(256), 0, stream>>>(node_sum, W_cls, b_cls, (float*)d_out);
}

// Round 3
// 281.366 us; speedup vs baseline: 2.8933x; 1.3272x over previous
//
#include <hip/hip_runtime.h>
#include <hip/hip_bf16.h>

// R3: k_ssm sequential scan (278us, VGPR-spilled, VALU-bound) -> Toeplitz MFMA
// conv GEMM. y[bn,h,t] = win*Sum_tau x[bn,tau]*K'[h,t-tau] + bin*cumK'[h,t],
// K'[0] += D (skip folded into tap 0). B-operand = 8 shift-aligned reversed
// copies of K' so every Toeplitz b-frag is one aligned bf16x8 global load.

#define B_  16
#define T_  354
#define N_  64
#define H_  128
#define NS_ 32
#define BN_ (B_*N_)          // 1024 sequences
#define TP_ 384              // padded tau range for A
#define KW_ 512              // padded Krev row length
#define TC_ 23               // t-chunk per k_glu block

typedef __attribute__((ext_vector_type(8))) short bf16x8;
typedef __attribute__((ext_vector_type(4))) float f32x4;

static __device__ __forceinline__ unsigned short f32_to_bf16(float f) {
    unsigned int u = __float_as_uint(f);
    unsigned int r = 0x7FFFu + ((u >> 16) & 1u);   // RNE
    return (unsigned short)((u + r) >> 16);
}

// ---------------------------------------------------------------------------
// K0: W_out f32 -> bf16 (layout unchanged [j][k])
// ---------------------------------------------------------------------------
__global__ void k_wprep(const float* __restrict__ W_out, unsigned short* __restrict__ Wbf) {
    int i = blockIdx.x * blockDim.x + threadIdx.x;
    if (i < 2 * H_ * H_) Wbf[i] = f32_to_bf16(W_out[i]);
}

// ---------------------------------------------------------------------------
// K0b: x (B,T,N) f32 -> xbf[bn][tau] bf16 (tau = t, padded to TP_ with zeros
// via prior memset). Coalesced reads (consecutive bn = consecutive n).
// ---------------------------------------------------------------------------
__global__ void k_xprep(const float* __restrict__ x, unsigned short* __restrict__ xbf) {
    int id = blockIdx.x * blockDim.x + threadIdx.x;   // t*1024 + bn
    if (id >= T_ * BN_) return;
    int t  = id >> 10;
    int bn = id & 1023;
    float v = x[(bn >> 6) * (T_ * N_) + t * N_ + (bn & 63)];
    xbf[bn * TP_ + t] = f32_to_bf16(v);
}

// ---------------------------------------------------------------------------
// K1: S4D kernel taps.  Block = one h, 512 threads (thread = tap index l).
//   K'[h,l] = 2*Sum_m Re(Cd[h,m] * exp(dtA*l))  (+ D[h] at l=0)
//   Krev_r[h][(353-l)+r] = bf16(K') for r=0..7  (shift-aligned reversed copies)
//   koff[t][h] = b_in[h] * cumsum_l<=t K'[h,l]  (LDS inclusive scan)
// ---------------------------------------------------------------------------
__global__ __launch_bounds__(512) void k_kern(
        const float* __restrict__ log_dt,
        const float* __restrict__ A_re, const float* __restrict__ A_im,
        const float* __restrict__ C_re, const float* __restrict__ C_im,
        const float* __restrict__ b_in, const float* __restrict__ D,
        unsigned short* __restrict__ Krev, float* __restrict__ koff) {
    const int h = blockIdx.x;
    const int l = threadIdx.x;

    float val = 0.0f;
    if (l < T_) {
        float dt = expf(log_dt[h]);
        float fl = (float)l;
#pragma unroll 4
        for (int m = 0; m < NS_; m++) {
            float are = A_re[h * NS_ + m], aim = A_im[h * NS_ + m];
            float dre = are * dt, dim = aim * dt;
            // Cd = C*(exp(dtA)-1)/A
            float er  = expf(dre);
            float c1, s1; __sincosf(dim, &s1, &c1);
            float e_re = er * c1, e_im = er * s1;
            float m_re = e_re - 1.0f, m_im = e_im;
            float inv  = 1.0f / (are * are + aim * aim);
            float q_re = (m_re * are + m_im * aim) * inv;
            float q_im = (m_im * are - m_re * aim) * inv;
            float c_r = C_re[h * NS_ + m], c_i = C_im[h * NS_ + m];
            float cdre = c_r * q_re - c_i * q_im;
            float cdim = c_r * q_im + c_i * q_re;
            // exp(dtA*l)
            float el = expf(dre * fl);
            float cl, sl; __sincosf(dim * fl, &sl, &cl);
            val += el * (cdre * cl - cdim * sl);
        }
        val *= 2.0f;
        if (l == 0) val += D[h];
    }

    // inclusive scan over l (Hillis-Steele, 512 threads)
    __shared__ float sc[512];
    sc[l] = (l < T_) ? val : 0.0f;
    __syncthreads();
    for (int off = 1; off < 512; off <<= 1) {
        float add = (l >= off) ? sc[l - off] : 0.0f;
        __syncthreads();
        sc[l] += add;
        __syncthreads();
    }

    if (l < T_) {
        koff[l * H_ + h] = b_in[h] * sc[l];
        unsigned short bv = f32_to_bf16(val);
#pragma unroll
        for (int r = 0; r < 8; r++)
            Krev[((size_t)r * H_ + h) * KW_ + (T_ - 1 - l) + r] = bv;
    }
}

// ---------------------------------------------------------------------------
// K2: Toeplitz conv GEMM.  Block = 128 bn x 128 h x ONE t; 4 waves, wave w
// owns h in [32w, 32w+32).  k-loop over tau-blocks (<= t/128), all operands
// streamed directly from L2-hot global (no LDS).  Epilogue: y = win*acc +
// koff, gelu(tanh), store bf16 to Y[q=t*BN+bn][h].
// ---------------------------------------------------------------------------
__global__ __launch_bounds__(256, 2) void k_conv(
        const unsigned short* __restrict__ xbf,    // [1024][TP_]
        const unsigned short* __restrict__ Krev,   // [8][128][KW_]
        const float* __restrict__ koff,            // [354][128]
        const float* __restrict__ W_in,            // win[h]
        unsigned short* __restrict__ Y) {
    const int tid  = threadIdx.x;
    const int w    = tid >> 6;
    const int lane = tid & 63;
    const int quad = lane >> 4;
    const int l16  = lane & 15;
    const int bn0  = blockIdx.x * 128;
    const int t    = blockIdx.y;
    const int h0   = w * 32;
    const int nkb  = (t >> 7) + 1;

    f32x4 acc[8][2];
#pragma unroll
    for (int mt = 0; mt < 8; mt++)
#pragma unroll
        for (int nt = 0; nt < 2; nt++) acc[mt][nt] = (f32x4){0.f, 0.f, 0.f, 0.f};

    for (int kb = 0; kb < nkb; kb++) {
        const int tau0 = kb << 7;
        const int s    = (T_ - 1) - t + tau0;      // >= 0
        const int r    = (-s) & 7;                 // align s+r to 8 elems (16B)
        const unsigned short* bb = Krev + (size_t)r * H_ * KW_ + (s + r);

#pragma unroll
        for (int ks = 0; ks < 4; ks++) {
            bf16x8 bfr[2];
#pragma unroll
            for (int nt = 0; nt < 2; nt++)
                bfr[nt] = *(const bf16x8*)(bb + (h0 + nt * 16 + l16) * KW_
                                           + ks * 32 + quad * 8);
#pragma unroll
            for (int mt = 0; mt < 8; mt++) {
                bf16x8 afr = *(const bf16x8*)(xbf + (size_t)(bn0 + mt * 16 + l16) * TP_
                                              + tau0 + ks * 32 + quad * 8);
                acc[mt][0] = __builtin_amdgcn_mfma_f32_16x16x32_bf16(afr, bfr[0], acc[mt][0], 0, 0, 0);
                acc[mt][1] = __builtin_amdgcn_mfma_f32_16x16x32_bf16(afr, bfr[1], acc[mt][1], 0, 0, 0);
            }
        }
    }

    float win[2], ko[2];
#pragma unroll
    for (int nt = 0; nt < 2; nt++) {
        int h = h0 + nt * 16 + l16;
        win[nt] = W_in[h];
        ko[nt]  = koff[t * H_ + h];
    }

#pragma unroll
    for (int mt = 0; mt < 8; mt++)
#pragma unroll
        for (int nt = 0; nt < 2; nt++)
#pragma unroll
            for (int rr = 0; rr < 4; rr++) {
                float v = fmaf(acc[mt][nt][rr], win[nt], ko[nt]);
                // gelu, tanh approximation (JAX default)
                float a  = 0.7978845608028654f * fmaf(0.044715f, v * v * v, v);
                float e  = __expf(2.0f * a);
                float th = 1.0f - 2.0f / (e + 1.0f);
                float g  = 0.5f * v * (1.0f + th);
                int bn = bn0 + mt * 16 + quad * 4 + rr;
                int h  = h0 + nt * 16 + l16;
                Y[((size_t)t * BN_ + bn) * H_ + h] = f32_to_bf16(g);
            }
}

// ---------------------------------------------------------------------------
// K3: MFMA GEMM  g = W_out·y (+bias), GLU, pool over t -> node_sum[bn][j].
// (unchanged from R2)
// ---------------------------------------------------------------------------
__global__ __launch_bounds__(256, 2) void k_glu(
        const unsigned short* __restrict__ Ybf,
        const unsigned short* __restrict__ Wbf,
        const float* __restrict__ b_out,
        float* __restrict__ node_sum) {
    __shared__ unsigned short W_lds[128 * 136];

    const int tid  = threadIdx.x;
    const int w    = tid >> 6;
    const int lane = tid & 63;
    const int quad = lane >> 4;
    const int l16  = lane & 15;
    const int bn0  = blockIdx.x * 32;
    const int t0   = blockIdx.y * TC_;

    bf16x8 bfrag[4][4];

    for (int p = 0; p < 2; p++) {
        __syncthreads();
#pragma unroll
        for (int it = 0; it < 16; it++) {
            int c  = it * 256 + tid;
            int r  = c >> 5;
            int k4 = (c & 31) * 4;
            uint2 v = *(const uint2*)(Wbf + (size_t)(p * 128 + r) * 128 + k4);
            *(uint2*)&W_lds[r * 136 + k4] = v;
        }
        __syncthreads();
#pragma unroll
        for (int nt = 0; nt < 2; nt++) {
            int r = 32 * w + 16 * nt + l16;
#pragma unroll
            for (int ks = 0; ks < 4; ks++)
                bfrag[p * 2 + nt][ks] = *(const bf16x8*)&W_lds[r * 136 + ks * 32 + quad * 8];
        }
    }

    float bo1[2], bo2[2];
#pragma unroll
    for (int p = 0; p < 2; p++) {
        bo1[p] = b_out[32 * w + 16 * p + l16];
        bo2[p] = b_out[128 + 32 * w + 16 * p + l16];
    }

    f32x4 zacc[2][2];
#pragma unroll
    for (int mt = 0; mt < 2; mt++)
#pragma unroll
        for (int p = 0; p < 2; p++) zacc[mt][p] = (f32x4){0.f, 0.f, 0.f, 0.f};

    for (int tt = 0; tt < TC_; tt++) {
        int t = t0 + tt;
        if (t >= T_) break;
        const unsigned short* yrow = Ybf + (size_t)(t * BN_ + bn0) * H_;

        bf16x8 afrag[2][4];
#pragma unroll
        for (int mt = 0; mt < 2; mt++)
#pragma unroll
            for (int ks = 0; ks < 4; ks++)
                afrag[mt][ks] = *(const bf16x8*)(yrow + (size_t)(16 * mt + l16) * H_
                                                 + ks * 32 + quad * 8);

        f32x4 acc[2][4];
#pragma unroll
        for (int mt = 0; mt < 2; mt++)
#pragma unroll
            for (int nt = 0; nt < 4; nt++) acc[mt][nt] = (f32x4){0.f, 0.f, 0.f, 0.f};

#pragma unroll
        for (int ks = 0; ks < 4; ks++)
#pragma unroll
            for (int nt = 0; nt < 4; nt++)
#pragma unroll
                for (int mt = 0; mt < 2; mt++)
                    acc[mt][nt] = __builtin_amdgcn_mfma_f32_16x16x32_bf16(
                        afrag[mt][ks], bfrag[nt][ks], acc[mt][nt], 0, 0, 0);

#pragma unroll
        for (int mt = 0; mt < 2; mt++)
#pragma unroll
            for (int p = 0; p < 2; p++)
#pragma unroll
                for (int r = 0; r < 4; r++) {
                    float a  = acc[mt][p][r] + bo1[p];
                    float bs = acc[mt][p + 2][r] + bo2[p];
                    float sg = 1.0f / (1.0f + __expf(-bs));
                    zacc[mt][p][r] += a * sg;
                }
    }

#pragma unroll
    for (int mt = 0; mt < 2; mt++)
#pragma unroll
        for (int p = 0; p < 2; p++)
#pragma unroll
            for (int r = 0; r < 4; r++) {
                int bn = bn0 + 16 * mt + quad * 4 + r;
                int j  = 32 * w + 16 * p + l16;
                atomicAdd(&node_sum[bn * H_ + j], zacc[mt][p][r]);
            }
}

// ---------------------------------------------------------------------------
// K4: logits (unchanged)
// ---------------------------------------------------------------------------
__global__ void k_cls(const float* __restrict__ node_sum,
                      const float* __restrict__ W_cls, const float* __restrict__ b_cls,
                      float* __restrict__ out) {
    const int b = blockIdx.x, tid = threadIdx.x;
    float s = 0.0f;
    for (int i = tid; i < N_ * H_; i += 256)
        s += node_sum[b * (N_ * H_) + i] * W_cls[i & (H_ - 1)];
    __shared__ float red[256];
    red[tid] = s;
    __syncthreads();
    for (int off = 128; off > 0; off >>= 1) {
        if (tid < off) red[tid] += red[tid + off];
        __syncthreads();
    }
    if (tid == 0) out[b] = red[0] * (1.0f / (354.0f * 64.0f)) + b_cls[0];
}

// ---------------------------------------------------------------------------
extern "C" void kernel_launch(void* const* d_in, const int* in_sizes, int n_in,
                              void* d_out, int out_size, void* d_ws, size_t ws_size,
                              hipStream_t stream) {
    const float* x      = (const float*)d_in[0];
    const float* W_in   = (const float*)d_in[1];
    const float* b_in   = (const float*)d_in[2];
    const float* log_dt = (const float*)d_in[3];
    const float* A_re   = (const float*)d_in[4];
    const float* A_im   = (const float*)d_in[5];
    const float* C_re   = (const float*)d_in[6];
    const float* C_im   = (const float*)d_in[7];
    const float* D      = (const float*)d_in[8];
    const float* W_out  = (const float*)d_in[9];
    const float* b_out  = (const float*)d_in[10];
    const float* W_cls  = (const float*)d_in[11];
    const float* b_cls  = (const float*)d_in[12];

    float* ws = (float*)d_ws;
    float*          node_sum = ws;                                   // 131072 f32
    float*          koff     = ws + 131072;                          // 45312 f32
    unsigned short* Wbf      = (unsigned short*)(ws + 176384);       // 32768 bf16
    unsigned short* xbf      = (unsigned short*)(ws + 192768);       // 1024*384 bf16
    unsigned short* Krev     = (unsigned short*)(ws + 389376);       // 8*128*512 bf16
    unsigned short* Y        = (unsigned short*)(ws + 651520);       // 362496*128 bf16

    hipMemsetAsync(node_sum, 0, (size_t)BN_ * H_ * sizeof(float), stream);
    hipMemsetAsync(xbf,  0, (size_t)BN_ * TP_ * 2, stream);
    hipMemsetAsync(Krev, 0, (size_t)8 * H_ * KW_ * 2, stream);

    k_wprep<<<dim3(2 * H_ * H_ / 256), dim3(256), 0, stream>>>(W_out, Wbf);
    k_xprep<<<dim3((T_ * BN_ + 255) / 256), dim3(256), 0, stream>>>(x, xbf);
    k_kern<<<dim3(H_), dim3(512), 0, stream>>>(
        log_dt, A_re, A_im, C_re, C_im, b_in, D, Krev, koff);
    k_conv<<<dim3(BN_ / 128, T_), dim3(256), 0, stream>>>(xbf, Krev, koff, W_in, Y);
    k_glu<<<dim3(BN_ / 32, (T_ + TC_ - 1) / TC_), dim3(256), 0, stream>>>(
        Y, Wbf, b_out, node_sum);
    k_cls<<<dim3(B_), dim3(256), 0, stream>>>(node_sum, W_cls, b_cls, (float*)d_out);
}